// Round 5
// baseline (1324.854 us; speedup 1.0000x reference)
//
#include <hip/hip_runtime.h>
#include <hip/hip_bf16.h>

// StabilityPredictorSchnet: B=4, L=384, H=128, F=384
// One block per (b,l). 6 k-tiles of 64 edge rows, 3 barriers/iter:
//   stage: hE fp32 tile -> regs (coalesced float4) -> cvt_pk -> sA bf16
//   GEMM1: sA[64x128] @ fw1 -> gelu -> sT1 (bf16)   [mfma 16x16x32 bf16]
//   GEMM2: sT1[64x384] @ fw2 -> gelu -> * h_V -> xc (register accum)
// Head MLP + last-block finalize fused.
// R4 lessons: (a) WRITE_SIZE 152MB scratch + VGPR pressure -> split each
// GEMM N-loop into 2 passes (acc[4][3]=48 AGPR live, peak unified ~115);
// (b) K-loop load->MFMA serialization -> double-buffered B-frag regs;
// (c) VALU 35% busy -> 7-op tanh-gelu (err ~1e-3 << 0.106 threshold);
// (d) global_load_lds showed 2x hE FETCH -> plain reg staging, one less
// barrier.

#define Bz 4
#define Lz 384
#define Hz 128
#define Fz 384
#define KT 64          // k-tile rows (edge rows per iteration)
#define NIT 6          // 384 / KT

typedef short bf16x8 __attribute__((ext_vector_type(8)));
typedef float f32x4 __attribute__((ext_vector_type(4)));

__device__ __forceinline__ unsigned short f2bf(float f) {
  unsigned int u = __float_as_uint(f);
  u += 0x7FFFu + ((u >> 16) & 1u);   // RNE bf16
  return (unsigned short)(u >> 16);
}

// tanh-form gelu, algebraically reduced:
// gelu(x) ~= x * (1 - 1/(exp2(x*(c1 + c2*x^2)) + 1)),
// c1 = 2*sqrt(2/pi)*log2(e), c2 = c1*0.044715.  7 VALU ops, |err|~1e-3.
__device__ __forceinline__ float gelu_f(float x) {
  const float c1 = 2.3022082f, c2 = 0.10294823f;
  float x2 = x * x;
  float u  = x * __builtin_fmaf(c2, x2, c1);
  float e  = __builtin_amdgcn_exp2f(u);
  float r  = __builtin_amdgcn_rcpf(e + 1.0f);
  return __builtin_fmaf(-x, r, x);
}

// ---- prep: zero acc/counter; pack fw1/fw2 into MFMA B-fragment order ----
// fw1P flat: ((t*4+ks)*64+lane)*8+j  = bf(fw1[(ks*32+(lane>>4)*8+j)*F + t*16+(lane&15)])
// fw2P flat: ((t*12+ks)*64+lane)*8+j = bf(fw2[...same...])
__global__ __launch_bounds__(256) void prep_kernel(
    const float* __restrict__ fw1, const float* __restrict__ fw2,
    unsigned short* __restrict__ fw1P, unsigned short* __restrict__ fw2P,
    float* __restrict__ accbuf, int* __restrict__ ctr)
{
  int e = blockIdx.x * 256 + threadIdx.x;
  if (e < 16) accbuf[e] = 0.0f;
  if (e == 16) *ctr = 0;
  if (e < 24 * 4 * 64 * 8) {
    int j = e & 7, lf = (e >> 3) & 63, ks = (e >> 9) & 3, t = e >> 11;
    int n = t * 16 + (lf & 15);
    int k = ks * 32 + (lf >> 4) * 8 + j;
    fw1P[e] = f2bf(fw1[(size_t)k * Fz + n]);
  } else if (e < 24 * 4 * 64 * 8 + 24 * 12 * 64 * 8) {
    int o = e - 24 * 4 * 64 * 8;
    int j = o & 7, lf = (o >> 3) & 63, r = o >> 9;
    int ks = r % 12, t = r / 12;
    int n = t * 16 + (lf & 15);
    int k = ks * 32 + (lf >> 4) * 8 + j;
    fw2P[o] = f2bf(fw2[(size_t)k * Fz + n]);
  }
}

__global__ __launch_bounds__(256, 2) void schnet_main(
    const float* __restrict__ hV, const float* __restrict__ hE,
    const float* __restrict__ mask,
    const unsigned short* __restrict__ fw1P, const float* __restrict__ fb1,
    const unsigned short* __restrict__ fw2P, const float* __restrict__ fb2,
    const float* __restrict__ hw1, const float* __restrict__ hb1,
    const float* __restrict__ hw2, const float* __restrict__ hb2,
    const float* __restrict__ hw3, const float* __restrict__ hb3,
    float* __restrict__ accbuf, int* __restrict__ ctr,
    float* __restrict__ out)
{
  const int bl   = blockIdx.x;
  const int b    = bl / Lz;
  const int l    = bl - b * Lz;
  const int tid  = threadIdx.x;
  const int wave = tid >> 6;
  const int lane = tid & 63;
  const int lr   = lane & 15;   // 16-index (row for A, col for B/C)
  const int quad = lane >> 4;   // 0..3

  __shared__ unsigned short sA[KT][136];   // hE tile bf16, 17408 B
  __shared__ unsigned short sT1[KT][392];  // gelu(hE@fw1) bf16, 50176 B
  __shared__ float sXC[Fz];
  __shared__ float sHp[2][Hz];
  __shared__ float sH1[Hz];
  __shared__ float sH2[64];
  __shared__ int   sLast;

  const float* hE_bl = hE + (size_t)bl * (Lz * Hz);
  const unsigned short* w1base = fw1P + (size_t)lane * 8;
  const unsigned short* w2base = fw2P + (size_t)lane * 8;

  float xc[6] = {0.f, 0.f, 0.f, 0.f, 0.f, 0.f};
  const f32x4 zero4 = {0.f, 0.f, 0.f, 0.f};

  for (int it = 0; it < NIT; ++it) {
    // (a) prev iter done: GEMM1 with sA, GEMM2 with sT1
    __syncthreads();

    // ---- stage: 8 coalesced float4 loads -> cvt_pk -> sA bf16 ----
    {
      const float* src = hE_bl + (size_t)it * (KT * Hz);
      float4 pf[8];
      #pragma unroll
      for (int j = 0; j < 8; ++j)
        pf[j] = *(const float4*)(src + 4 * tid + 1024 * j);
      #pragma unroll
      for (int j = 0; j < 8; ++j) {
        int f = 4 * tid + 1024 * j;
        int row = f >> 7, col = f & 127;
        __hip_bfloat162 p0 = __float22bfloat162_rn({pf[j].x, pf[j].y});
        __hip_bfloat162 p1 = __float22bfloat162_rn({pf[j].z, pf[j].w});
        uint2 w;
        w.x = *(unsigned int*)&p0;
        w.y = *(unsigned int*)&p1;
        *(uint2*)&sA[row][col] = w;
      }
    }
    // (b) sA ready
    __syncthreads();

    // ====== GEMM1: sA[64x128] @ fw1, 2 N-passes, B-frag double-buffer ======
    #pragma unroll
    for (int nh = 0; nh < 2; ++nh) {
      f32x4 acc[4][3];
      #pragma unroll
      for (int mt = 0; mt < 4; ++mt)
        #pragma unroll
        for (int i = 0; i < 3; ++i) acc[mt][i] = zero4;

      bf16x8 bq[2][3];
      #pragma unroll
      for (int i = 0; i < 3; ++i)
        bq[0][i] = *(const bf16x8*)(w1base +
                      (size_t)(((wave * 6 + nh * 3 + i) * 4) * 64) * 8);

      #pragma unroll
      for (int ks = 0; ks < 4; ++ks) {
        const int cur = ks & 1;
        if (ks + 1 < 4) {
          #pragma unroll
          for (int i = 0; i < 3; ++i)
            bq[cur ^ 1][i] = *(const bf16x8*)(w1base +
                (size_t)(((wave * 6 + nh * 3 + i) * 4 + ks + 1) * 64) * 8);
        }
        const int k0 = ks * 32 + quad * 8;
        bf16x8 afr[4];
        #pragma unroll
        for (int mt = 0; mt < 4; ++mt)
          afr[mt] = *(const bf16x8*)(&sA[mt * 16 + lr][k0]);
        #pragma unroll
        for (int mt = 0; mt < 4; ++mt)
          #pragma unroll
          for (int i = 0; i < 3; ++i)
            acc[mt][i] = __builtin_amdgcn_mfma_f32_16x16x32_bf16(
                afr[mt], bq[cur][i], acc[mt][i], 0, 0, 0);
      }
      // epi1: bias+gelu -> sT1. C/D: row=quad*4+r, col=lr (m89)
      #pragma unroll
      for (int i = 0; i < 3; ++i) {
        const int n = wave * 96 + (nh * 3 + i) * 16 + lr;
        const float bias = fb1[n];
        #pragma unroll
        for (int mt = 0; mt < 4; ++mt)
          #pragma unroll
          for (int r = 0; r < 4; ++r)
            sT1[mt * 16 + quad * 4 + r][n] =
                f2bf(gelu_f(acc[mt][i][r] + bias));
      }
    }
    // (c) sT1 ready
    __syncthreads();

    // ====== GEMM2: sT1[64x384] @ fw2, 2 N-passes, B-frag double-buffer ======
    #pragma unroll
    for (int nh = 0; nh < 2; ++nh) {
      f32x4 acc[4][3];
      #pragma unroll
      for (int mt = 0; mt < 4; ++mt)
        #pragma unroll
        for (int i = 0; i < 3; ++i) acc[mt][i] = zero4;

      bf16x8 bq[2][3];
      #pragma unroll
      for (int i = 0; i < 3; ++i)
        bq[0][i] = *(const bf16x8*)(w2base +
                      (size_t)(((wave * 6 + nh * 3 + i) * 12) * 64) * 8);

      #pragma unroll
      for (int ks = 0; ks < 12; ++ks) {
        const int cur = ks & 1;
        if (ks + 1 < 12) {
          #pragma unroll
          for (int i = 0; i < 3; ++i)
            bq[cur ^ 1][i] = *(const bf16x8*)(w2base +
                (size_t)(((wave * 6 + nh * 3 + i) * 12 + ks + 1) * 64) * 8);
        }
        const int k0 = ks * 32 + quad * 8;
        bf16x8 afr[4];
        #pragma unroll
        for (int mt = 0; mt < 4; ++mt)
          afr[mt] = *(const bf16x8*)(&sT1[mt * 16 + lr][k0]);
        #pragma unroll
        for (int mt = 0; mt < 4; ++mt)
          #pragma unroll
          for (int i = 0; i < 3; ++i)
            acc[mt][i] = __builtin_amdgcn_mfma_f32_16x16x32_bf16(
                afr[mt], bq[cur][i], acc[mt][i], 0, 0, 0);
      }
      // epi2: bias+gelu, * h_V[b,k,n], accumulate per column
      #pragma unroll
      for (int i = 0; i < 3; ++i) {
        const int nl = nh * 3 + i;
        const int n  = wave * 96 + nl * 16 + lr;
        const float bias = fb2[n];
        float part = 0.f;
        #pragma unroll
        for (int mt = 0; mt < 4; ++mt) {
          const float* hv =
              hV + ((size_t)b * Lz + it * KT + mt * 16 + quad * 4) * Fz + n;
          #pragma unroll
          for (int r = 0; r < 4; ++r) {
            float w = gelu_f(acc[mt][i][r] + bias);
            part += w * hv[(size_t)r * Fz];
          }
        }
        xc[nl] += part;
      }
    }
  }

  // reduce xc across quads -> sXC
  #pragma unroll
  for (int nl = 0; nl < 6; ++nl) {
    float v = xc[nl];
    v += __shfl_xor(v, 16);
    v += __shfl_xor(v, 32);
    if (quad == 0) sXC[wave * 96 + nl * 16 + lr] = v;
  }
  __syncthreads();

  // ---- head MLP (fp32, tiny) ----
  {
    int i = tid & 127;
    int half = tid >> 7;
    float a = 0.f;
    const int f0 = half * 192;
    for (int f = f0; f < f0 + 192; ++f) a += sXC[f] * hw1[f * Hz + i];
    sHp[half][i] = a;
  }
  __syncthreads();
  if (tid < Hz) sH1[tid] = gelu_f(sHp[0][tid] + sHp[1][tid] + hb1[tid]);
  __syncthreads();
  if (tid < 64) {
    float a = hb2[tid];
    for (int i = 0; i < Hz; ++i) a += sH1[i] * hw2[i * 64 + tid];
    sH2[tid] = gelu_f(a);
  }
  __syncthreads();
  if (wave == 0) {
    float v = sH2[lane] * hw3[lane];
    #pragma unroll
    for (int off = 32; off >= 1; off >>= 1) v += __shfl_xor(v, off);
    if (lane == 0) {
      float pred = v + hb3[0];
      atomicAdd(&accbuf[b], pred * mask[b * Lz + l]);
      __threadfence();
      sLast = (atomicAdd(ctr, 1) == (Bz * Lz - 1));
    }
  }
  __syncthreads();

  // ---- last block: finalize all 4 batches ----
  if (sLast && wave < Bz) {
    float s = 0.f;
    #pragma unroll
    for (int k = 0; k < Lz / 64; ++k) s += mask[wave * Lz + k * 64 + lane];
    #pragma unroll
    for (int off = 32; off >= 1; off >>= 1) s += __shfl_xor(s, off);
    if (lane == 0) {
      float vl = s < 1.0f ? 1.0f : s;
      float a = atomicAdd(&accbuf[wave], 0.0f);   // coherent read
      out[wave] = a / sqrtf(vl);
    }
  }
}

extern "C" void kernel_launch(void* const* d_in, const int* in_sizes, int n_in,
                              void* d_out, int out_size, void* d_ws, size_t ws_size,
                              hipStream_t stream)
{
  const float* hV   = (const float*)d_in[0];
  const float* hE   = (const float*)d_in[1];
  const float* mask = (const float*)d_in[2];
  const float* fw1  = (const float*)d_in[3];
  const float* fb1  = (const float*)d_in[4];
  const float* fw2  = (const float*)d_in[5];
  const float* fb2  = (const float*)d_in[6];
  const float* hw1  = (const float*)d_in[7];
  const float* hb1  = (const float*)d_in[8];
  const float* hw2  = (const float*)d_in[9];
  const float* hb2  = (const float*)d_in[10];
  const float* hw3  = (const float*)d_in[11];
  const float* hb3  = (const float*)d_in[12];
  float* out = (float*)d_out;

  // ws: [0,64) accbuf; [64,68) ctr; fw1P @1024 (96 KB); fw2P after (288 KB)
  float* accbuf = (float*)d_ws;
  int*   ctr    = (int*)((char*)d_ws + 64);
  unsigned short* fw1P = (unsigned short*)((char*)d_ws + 1024);
  unsigned short* fw2P = fw1P + 24 * 4 * 64 * 8;

  prep_kernel<<<768, 256, 0, stream>>>(fw1, fw2, fw1P, fw2P, accbuf, ctr);
  schnet_main<<<Bz * Lz, 256, 0, stream>>>(hV, hE, mask, fw1P, fb1, fw2P, fb2,
                                           hw1, hb1, hw2, hb2, hw3, hb3,
                                           accbuf, ctr, out);
}